// Round 5
// baseline (648.622 us; speedup 1.0000x reference)
//
#include <hip/hip_runtime.h>
#include <stdint.h>

#define K_DIM 1024
#define N_DIM 1024

// GEMM geometry: 128x128 tile, BK=32, 4 waves (2M x 2N, 64x64 each),
// 256 threads, 2-stage LDS ring (32 KiB) -> 4 blocks/CU (4 independent
// barrier domains; m114 cross-block overlap is the latency-hiding mechanism).
// A (x, fp32) is reg-staged + converted to bf16 in-kernel (fused convert_x).
#define BM 128
#define BN 128
#define BK 32
#define NKT (K_DIM / BK)      // 32 k-tiles
#define NBUF 2
#define A_TILE (BM * BK)      // 4096 ushorts = 8 KiB
#define B_TILE (BN * BK)

typedef __attribute__((ext_vector_type(8))) __bf16 bf16x8;
typedef __attribute__((ext_vector_type(4))) float f32x4;

// Static device storage (fully rewritten every call; BSS, no load-time cost)
__device__ __align__(16) unsigned short g_wq[N_DIM * K_DIM];  // ternary W as bf16 bits
__device__ double g_partial[256];
__device__ float g_scale;

__device__ __forceinline__ unsigned int pack_bf16(float hi, float lo) {
  // (trunc_bf16(hi) << 16) | trunc_bf16(lo) in one v_perm_b32
  return __builtin_amdgcn_perm(__float_as_uint(hi), __float_as_uint(lo), 0x07060302u);
}

// ---- Kernel 1: partial sums of |w| (double accumulation, deterministic) ----
__global__ void absum_kernel(const float* __restrict__ w) {
  const int tid = threadIdx.x, bid = blockIdx.x;
  const float4* w4 = (const float4*)w;  // 262144 float4s total
  double s = 0.0;
#pragma unroll
  for (int i = 0; i < 4; i++) {
    float4 v = w4[bid * 1024 + i * 256 + tid];
    s += (double)fabsf(v.x) + (double)fabsf(v.y) + (double)fabsf(v.z) + (double)fabsf(v.w);
  }
#pragma unroll
  for (int o = 32; o > 0; o >>= 1) s += __shfl_down(s, o);
  __shared__ double sm[4];
  if ((tid & 63) == 0) sm[tid >> 6] = s;
  __syncthreads();
  if (tid == 0) g_partial[bid] = sm[0] + sm[1] + sm[2] + sm[3];
}

// ---- Kernel 2: final reduce -> scale = max(mean|w|, 1e-5) ----
__global__ void scale_kernel() {
  const int tid = threadIdx.x;
  double v = g_partial[tid];
#pragma unroll
  for (int o = 32; o > 0; o >>= 1) v += __shfl_down(v, o);
  __shared__ double sm[4];
  if ((tid & 63) == 0) sm[tid >> 6] = v;
  __syncthreads();
  if (tid == 0) {
    double total = sm[0] + sm[1] + sm[2] + sm[3];
    double mean = total * (1.0 / 1048576.0);  // exact pow2 divide
    g_scale = (float)fmax(mean, 1e-5);
  }
}

// ---- Kernel 3: quantize W -> ternary bf16 {-1,0,1} (exact in bf16) ----
__global__ void quant_kernel(const float* __restrict__ w) {
  const int idx = blockIdx.x * 256 + threadIdx.x;  // x4 floats
  const float s = g_scale;
  float4 v = ((const float4*)w)[idx];
  float q0 = fminf(1.f, fmaxf(-1.f, rintf(v.x / s)));
  float q1 = fminf(1.f, fmaxf(-1.f, rintf(v.y / s)));
  float q2 = fminf(1.f, fmaxf(-1.f, rintf(v.z / s)));
  float q3 = fminf(1.f, fmaxf(-1.f, rintf(v.w / s)));
  ushort4 o;
  o.x = (unsigned short)(__float_as_uint(q0) >> 16);
  o.y = (unsigned short)(__float_as_uint(q1) >> 16);
  o.z = (unsigned short)(__float_as_uint(q2) >> 16);
  o.w = (unsigned short)(__float_as_uint(q3) >> 16);
  ((ushort4*)g_wq)[idx] = o;
}

// ---- Kernel 4: GEMM  C[M,N] = (bf16(x)[M,K] @ Wq[N,K]^T) * scale ----
// One vmcnt-counted gate + barrier per K-tile; fused fp32->bf16 A-staging
// (global fp32 -> v_perm pack -> swizzled ds_write_b128); B via verified
// global_load_lds + source-permute swizzle (0 bank conflicts measured).
__global__ __launch_bounds__(256, 4) void bitlinear_gemm(const float* __restrict__ x,
                                                         float* __restrict__ C) {
  __shared__ __align__(16) unsigned short As[NBUF * A_TILE];  // 16 KiB
  __shared__ __align__(16) unsigned short Bs[NBUF * B_TILE];  // 16 KiB

  const int tid  = threadIdx.x;
  const int lane = tid & 63;
  const int wave = tid >> 6;   // 0..3
  const int wm   = (wave >> 1) * 64;  // row offset of wave tile
  const int wn   = (wave & 1) * 64;   // col offset of wave tile
  const int lm   = lane & 15;
  const int lq   = lane >> 4;

  // XCD-locality swizzle (nwg = 4096, divisible by 8 -> bijective):
  // 8 consecutive logical blocks (one XCD) share one A-panel (fp32 panel =
  // 512 KB, L2-resident) and sweep the 8 n-tiles; g_wq (2 MB) L2-resident.
  const int b       = blockIdx.x;
  const int cpx     = (int)(gridDim.x >> 3);  // 512
  const int logical = (b & 7) * cpx + (b >> 3);
  const int mt      = logical >> 3;  // N_DIM/BN == 8 n-tiles
  const int nt      = logical & 7;
  const int m0      = mt * BM;
  const int n0      = nt * BN;

  f32x4 acc[4][4];
#pragma unroll
  for (int i = 0; i < 4; i++)
#pragma unroll
    for (int j = 0; j < 4; j++) acc[i][j] = (f32x4){0.f, 0.f, 0.f, 0.f};

  // --- B staging (verified path): glds w=16, source-permute swizzle ------
  const int cswz = ((lane & 3) ^ ((lane >> 3) & 3)) * 8;  // ushort offset
  const unsigned short* bSrc =
      g_wq + (size_t)(n0 + wave * 32 + (lane >> 2)) * K_DIM + cswz;
  const int ldsDst = wave * 32 * BK;  // ushort offset of this wave's rows

#define STAGE_B(tt, bb)                                                        \
  do {                                                                         \
    const unsigned short* s_ = bSrc + (tt) * BK;                               \
    unsigned short* d_ = &Bs[(bb) * B_TILE + ldsDst];                          \
    __builtin_amdgcn_global_load_lds(                                          \
        (const __attribute__((address_space(1))) unsigned int*)s_,             \
        (__attribute__((address_space(3))) unsigned int*)d_, 16, 0, 0);        \
    __builtin_amdgcn_global_load_lds(                                          \
        (const __attribute__((address_space(1))) unsigned int*)(s_ + 16 * K_DIM), \
        (__attribute__((address_space(3))) unsigned int*)(d_ + 16 * BK), 16, 0, 0); \
  } while (0)

  // --- A staging (fused convert): thread t -> row t>>1, k-half t&1.
  // 4x global_load_dwordx4 fp32 (64 B) -> 8x v_perm -> 2x ds_write_b128 to
  // chunks (2h+i)^((row>>1)&3); write pattern hits all 8 bank-groups
  // uniformly (8 lanes each, minimal for b128) and matches read-side XOR.
  const int arow = tid >> 1;                      // row in tile (0..127)
  const int ah   = tid & 1;                       // k-half (16 floats)
  const int aswz = (tid >> 2) & 3;                // ((arow>>1)&3)
  const float4* aGlb =
      (const float4*)(x + (size_t)(m0 + arow) * K_DIM + ah * 16);
  const int wo0 = arow * BK + (((2 * ah) ^ aswz) * 8);      // ushort offsets
  const int wo1 = arow * BK + (((2 * ah + 1) ^ aswz) * 8);

  float4 aR0, aR1, aR2, aR3;  // in-flight A k-window (16 floats)

#define LOAD_A(tt)                                                             \
  do {                                                                         \
    const float4* p_ = aGlb + (tt) * 8;                                        \
    aR0 = p_[0]; aR1 = p_[1]; aR2 = p_[2]; aR3 = p_[3];                        \
  } while (0)

#define CVT_WRITE_A(bb)                                                        \
  do {                                                                         \
    uint4 p0_, p1_;                                                            \
    p0_.x = pack_bf16(aR0.y, aR0.x); p0_.y = pack_bf16(aR0.w, aR0.z);          \
    p0_.z = pack_bf16(aR1.y, aR1.x); p0_.w = pack_bf16(aR1.w, aR1.z);          \
    p1_.x = pack_bf16(aR2.y, aR2.x); p1_.y = pack_bf16(aR2.w, aR2.z);          \
    p1_.z = pack_bf16(aR3.y, aR3.x); p1_.w = pack_bf16(aR3.w, aR3.z);          \
    *(uint4*)&As[(bb) * A_TILE + wo0] = p0_;                                   \
    *(uint4*)&As[(bb) * A_TILE + wo1] = p1_;                                   \
  } while (0)

  // --- LDS read addressing (swizzled; verified formula: 0 conflicts) -----
  const int xorc = (((lm >> 1) & 3) ^ lq) * 8;
  const int aRd  = (wm + lm) * BK + xorc;
  const int bRd  = (wn + lm) * BK + xorc;

  // --- Prologue: stage tile 0 into buf 0; preload A(1) regs ---------------
  // Issue order [A0 x4, B0 x2, (cvt waits A0), A1 x4]; gate vmcnt(4)
  // completes A0+B0, leaves A1 in flight; lgkm drain publishes A0 writes.
  LOAD_A(0);
  STAGE_B(0, 0);
  CVT_WRITE_A(0);
  LOAD_A(1);
  asm volatile("s_waitcnt vmcnt(4) lgkmcnt(0)\n\ts_barrier" ::: "memory");

  int buf = 0;
#pragma unroll 1
  for (int t = 0; t < NKT; ++t) {
    const unsigned short* Ab = &As[buf * A_TILE + aRd];
    const unsigned short* Bb = &Bs[buf * B_TILE + bRd];

    // Frag reads for tile t (8 x ds_read_b128)
    bf16x8 bfr[4], af[4];
#pragma unroll
    for (int nf = 0; nf < 4; ++nf) bfr[nf] = *(const bf16x8*)(Bb + nf * 16 * BK);
#pragma unroll
    for (int mf = 0; mf < 4; ++mf) af[mf] = *(const bf16x8*)(Ab + mf * 16 * BK);

    // Stage tile t+1 into buf^1; preload A(t+2) regs
    if (t < NKT - 1) {
      CVT_WRITE_A(buf ^ 1);   // uses A(t+1) regs (loaded one tile ago)
      STAGE_B(t + 1, buf ^ 1);
    }
    if (t < NKT - 2) LOAD_A(t + 2);

    __builtin_amdgcn_s_setprio(1);
#pragma unroll
    for (int mf = 0; mf < 4; ++mf)
#pragma unroll
      for (int nf = 0; nf < 4; ++nf)
        acc[mf][nf] = __builtin_amdgcn_mfma_f32_16x16x32_bf16(af[mf], bfr[nf],
                                                              acc[mf][nf], 0, 0, 0);
    __builtin_amdgcn_s_setprio(0);

    // Gate for tile t+1: B(t+1) glds done (A(t+2) reg-loads may stay in
    // flight); lgkmcnt(0) drains own frag reads of buf and publishes the
    // A ds_writes -> next tile may safely read buf^1 and overwrite buf.
    if (t < NKT - 2)
      asm volatile("s_waitcnt vmcnt(4) lgkmcnt(0)\n\ts_barrier" ::: "memory");
    else if (t < NKT - 1)
      asm volatile("s_waitcnt vmcnt(0) lgkmcnt(0)\n\ts_barrier" ::: "memory");

    buf ^= 1;
  }
#undef STAGE_B
#undef LOAD_A
#undef CVT_WRITE_A

  // Epilogue: C/D layout col=lane&15, row=(lane>>4)*4+r; apply scale here
  const float s    = g_scale;
  const int   crow = m0 + wm + lq * 4;
  const int   ccol = n0 + wn + lm;
#pragma unroll
  for (int mf = 0; mf < 4; ++mf) {
#pragma unroll
    for (int nf = 0; nf < 4; ++nf) {
#pragma unroll
      for (int r = 0; r < 4; ++r) {
        C[(size_t)(crow + mf * 16 + r) * N_DIM + (ccol + nf * 16)] =
            acc[mf][nf][r] * s;
      }
    }
  }
}

extern "C" void kernel_launch(void* const* d_in, const int* in_sizes, int n_in,
                              void* d_out, int out_size, void* d_ws, size_t ws_size,
                              hipStream_t stream) {
  const float* x = (const float*)d_in[0];   // [M, 1024] fp32
  const float* w = (const float*)d_in[1];   // [1024, 1024] fp32
  float* out = (float*)d_out;               // [M, 1024] fp32
  const int M = in_sizes[0] / K_DIM;        // 65536

  hipLaunchKernelGGL(absum_kernel, dim3(256), dim3(256), 0, stream, w);
  hipLaunchKernelGGL(scale_kernel, dim3(1), dim3(256), 0, stream);
  hipLaunchKernelGGL(quant_kernel, dim3(1024), dim3(256), 0, stream, w);
  hipLaunchKernelGGL(bitlinear_gemm,
                     dim3((unsigned)(((size_t)M / BM) * (N_DIM / BN))),
                     dim3(256), 0, stream, x, out);
}